// Round 9
// baseline (255.417 us; speedup 1.0000x reference)
//
#include <hip/hip_runtime.h>
#include <math.h>

#define TAU_F 32.0f

typedef __attribute__((ext_vector_type(8))) _Float16 half8;
typedef __attribute__((ext_vector_type(2))) __fp16 half2v;
typedef __attribute__((ext_vector_type(4))) float f32x4;

union HU { uint4 u; half8 v; };

__device__ __forceinline__ void sync_lds_only() {
    // CK-style block_sync_lds: drain LDS ops, leave VMEM (vmcnt) in flight.
    asm volatile("s_waitcnt lgkmcnt(0)" ::: "memory");
    __builtin_amdgcn_s_barrier();
}

// ============ Kernel 1: G partials, fp32 VALU, no atomics (unchanged) ============
// P[ks][192][2048], ks=4. Rows: 0..89 topic, 90..95 zero, 96..185 domain, 186..191 zero.
__global__ __launch_bounds__(256) void gproj2(
    const float* __restrict__ Wt, const float* __restrict__ Wd,
    const float* __restrict__ mem, const int* __restrict__ cat,
    float* __restrict__ P)
{
    __shared__ float Ml[96 * 36];
    __shared__ float Wl[32 * 68];

    const int bid = blockIdx.x;
    const int mat = bid >> 7;
    const int ks  = (bid >> 5) & 3;
    const int ct  = bid & 31;
    const int c0  = ct * 64;
    const int tid = threadIdx.x;
    const float* __restrict__ W = mat ? Wd : Wt;

    const int tr = tid >> 4;
    const int tc = tid & 15;

    float acc[6][4];
    #pragma unroll
    for (int j = 0; j < 6; ++j)
        #pragma unroll
        for (int q = 0; q < 4; ++q) acc[j][q] = 0.f;

    for (int ch = 0; ch < 6; ++ch) {
        __syncthreads();
        #pragma unroll
        for (int p = 0; p < 3; ++p) {
            const int idx = tid + 256 * p;
            const int r   = idx >> 3;
            const int kq  = idx & 7;
            float4 v = make_float4(0.f, 0.f, 0.f, 0.f);
            if (r < 90) {
                const int d = r / 10;
                const int mrow = cat[d] * 10 + (r - d * 10);
                v = *(const float4*)(mem + (size_t)mrow * 768 + ks * 192 + ch * 32 + kq * 4);
            }
            *(float4*)(Ml + r * 36 + kq * 4) = v;
        }
        #pragma unroll
        for (int p = 0; p < 2; ++p) {
            const int idx = tid + 256 * p;
            const int e   = idx >> 4;
            const int c4  = (idx & 15) * 4;
            *(float4*)(Wl + e * 68 + c4) =
                *(const float4*)(W + (size_t)(ks * 192 + ch * 32 + e) * 2048 + c0 + c4);
        }
        __syncthreads();

        #pragma unroll
        for (int e = 0; e < 32; e += 4) {
            float4 m4[6], w4[4];
            #pragma unroll
            for (int j = 0; j < 6; ++j) m4[j] = *(const float4*)(Ml + (tr * 6 + j) * 36 + e);
            #pragma unroll
            for (int q = 0; q < 4; ++q) w4[q] = *(const float4*)(Wl + (e + q) * 68 + tc * 4);
            #pragma unroll
            for (int j = 0; j < 6; ++j) {
                const float mv[4] = {m4[j].x, m4[j].y, m4[j].z, m4[j].w};
                #pragma unroll
                for (int q = 0; q < 4; ++q) {
                    acc[j][0] = fmaf(mv[q], w4[q].x, acc[j][0]);
                    acc[j][1] = fmaf(mv[q], w4[q].y, acc[j][1]);
                    acc[j][2] = fmaf(mv[q], w4[q].z, acc[j][2]);
                    acc[j][3] = fmaf(mv[q], w4[q].w, acc[j][3]);
                }
            }
        }
    }

    #pragma unroll
    for (int j = 0; j < 6; ++j) {
        float4 v = make_float4(acc[j][0], acc[j][1], acc[j][2], acc[j][3]);
        *(float4*)(P + (size_t)ks * 393216 + (size_t)(mat * 96 + tr * 6 + j) * 2048 + c0 + tc * 4) = v;
    }
}

// ============ Kernel 2: reduce partials -> f16 hi/lo, fragment-major (unchanged) ============
// frag f = (kc*12 + nq*3 + j)*2 + plane; addr(halfs) = f*512 + lq*128 + lm*8
__global__ __launch_bounds__(256) void split_g3(
    const float* __restrict__ P, unsigned short* __restrict__ gB)
{
    const int u  = blockIdx.x * 256 + threadIdx.x;  // 0..49151
    const int n  = u >> 8;                          // 0..191
    const int k0 = (u & 255) * 8;                   // 0..2040

    float s[8] = {0.f, 0.f, 0.f, 0.f, 0.f, 0.f, 0.f, 0.f};
    #pragma unroll
    for (int ks = 0; ks < 4; ++ks) {
        const float4 a = *(const float4*)(P + (size_t)ks * 393216 + (size_t)n * 2048 + k0);
        const float4 b = *(const float4*)(P + (size_t)ks * 393216 + (size_t)n * 2048 + k0 + 4);
        s[0] += a.x; s[1] += a.y; s[2] += a.z; s[3] += a.w;
        s[4] += b.x; s[5] += b.y; s[6] += b.z; s[7] += b.w;
    }
    union { _Float16 h[8]; uint4 u4; } hi, lo;
    #pragma unroll
    for (int e = 0; e < 8; ++e) {
        const _Float16 h = (_Float16)s[e];   // RNE
        hi.h[e] = h;
        lo.h[e] = (_Float16)(s[e] - (float)h);
    }
    const int kc = k0 >> 5;
    const int lq = (k0 >> 3) & 3;
    const int nq = n / 48;
    const int rm = n - nq * 48;
    const int j  = rm >> 4;
    const int lm = rm & 15;
    const size_t fH = (size_t)((kc * 12 + nq * 3 + j) * 2 + 0) * 512 + lq * 128 + lm * 8;
    const size_t fL = (size_t)((kc * 12 + nq * 3 + j) * 2 + 1) * 512 + lq * 128 + lm * 8;
    *(uint4*)(gB + fH) = hi.u4;
    *(uint4*)(gB + fL) = lo.u4;
}

// ============ Kernel 3: full-K raw-barrier split-f16 MFMA + in-kernel epilogue ============
// 256 blocks (one 64-row tile each, 1/CU), 256 thr = 4 waves; role nq=(w+bid)&3:
// nq<2 topic cols (exact 3-pass), nq>=2 domain cols (1-pass hi-only).
// Barriers: s_waitcnt lgkmcnt(0)+s_barrier only — global prefetch rides through.
#define SPAD 197

__global__ __launch_bounds__(256, 2) void fused_mfma7(
    const float* __restrict__ feat, const unsigned short* __restrict__ gB,
    float* __restrict__ out)
{
    __shared__ __align__(16) char smem[50688];  // staging 20480 B  U  scores 64*197*4
    __shared__ float ssqf[64];
    unsigned short* aS = (unsigned short*)smem; // [(buf*2+plane)*64+row]*40 + kf  (halfs)
    float* scores = (float*)smem;               // [64][SPAD]

    const int tid  = threadIdx.x;
    const int row0 = blockIdx.x * 64;
    const int w  = tid >> 6, l = tid & 63;
    const int lm = l & 15,  lq = l >> 4;
    const int nq = (w + blockIdx.x) & 3;        // role rotation across blocks
    const bool topic = (nq < 2);

    // staging: thread handles rows srow (lo half) and srow+32 (hi half), floats skf..skf+3
    const int srow = tid >> 3;                  // 0..31
    const int skf  = (tid & 7) * 4;             // 0,4,...,28

    f32x4 acc[4][3];
    #pragma unroll
    for (int i = 0; i < 4; ++i)
        #pragma unroll
        for (int j = 0; j < 3; ++j) acc[i][j] = (f32x4)0.f;
    float ssq0 = 0.f, ssq1 = 0.f;

    const float* fb0 = feat + (size_t)(row0 + srow) * 2048 + skf;
    const float* fb1 = feat + (size_t)(row0 + 32 + srow) * 2048 + skf;
    const unsigned short* bbase = gB + nq * 3072 + l * 8;   // + kc*12288 + j*1024 + p*512

    // convert+stage: va=row srow, vb=row srow+32 -> hi/lo planes of buf
    auto cw = [&](int buf, float4 va, float4 vb) {
        union { half2v h2[2]; uint2 u2; } h0, l0, h1, l1;
        ssq0 = fmaf(va.x, va.x, ssq0); ssq0 = fmaf(va.y, va.y, ssq0);
        ssq0 = fmaf(va.z, va.z, ssq0); ssq0 = fmaf(va.w, va.w, ssq0);
        ssq1 = fmaf(vb.x, vb.x, ssq1); ssq1 = fmaf(vb.y, vb.y, ssq1);
        ssq1 = fmaf(vb.z, vb.z, ssq1); ssq1 = fmaf(vb.w, vb.w, ssq1);
        half2v a01 = __builtin_amdgcn_cvt_pkrtz(va.x, va.y);
        half2v a23 = __builtin_amdgcn_cvt_pkrtz(va.z, va.w);
        h0.h2[0] = a01; h0.h2[1] = a23;
        l0.h2[0] = __builtin_amdgcn_cvt_pkrtz(va.x - (float)a01[0], va.y - (float)a01[1]);
        l0.h2[1] = __builtin_amdgcn_cvt_pkrtz(va.z - (float)a23[0], va.w - (float)a23[1]);
        half2v b01 = __builtin_amdgcn_cvt_pkrtz(vb.x, vb.y);
        half2v b23 = __builtin_amdgcn_cvt_pkrtz(vb.z, vb.w);
        h1.h2[0] = b01; h1.h2[1] = b23;
        l1.h2[0] = __builtin_amdgcn_cvt_pkrtz(vb.x - (float)b01[0], vb.y - (float)b01[1]);
        l1.h2[1] = __builtin_amdgcn_cvt_pkrtz(vb.z - (float)b23[0], vb.w - (float)b23[1]);
        unsigned short* pH = aS + (size_t)((buf * 2 + 0) * 64) * 40;
        unsigned short* pL = aS + (size_t)((buf * 2 + 1) * 64) * 40;
        *(uint2*)(pH + srow * 40 + skf)        = h0.u2;
        *(uint2*)(pH + (srow + 32) * 40 + skf) = h1.u2;
        *(uint2*)(pL + srow * 40 + skf)        = l0.u2;
        *(uint2*)(pL + (srow + 32) * 40 + skf) = l1.u2;
    };

    // ---- prologue ----
    float4 a00 = *(const float4*)(fb0);
    float4 a01 = *(const float4*)(fb1);
    float4 a10 = *(const float4*)(fb0 + 32);
    float4 a11 = *(const float4*)(fb1 + 32);
    uint4 bh[3], bl[3];
    #pragma unroll
    for (int j = 0; j < 3; ++j) bh[j] = *(const uint4*)(bbase + j * 1024);
    if (topic) {
        #pragma unroll
        for (int j = 0; j < 3; ++j) bl[j] = *(const uint4*)(bbase + j * 1024 + 512);
    }
    cw(0, a00, a01);
    sync_lds_only();

    for (int kc = 0; kc < 64; ++kc) {
        // B loads for kc+1 (never drained at barriers)
        const int kb = (kc + 1 < 64) ? kc + 1 : 63;
        uint4 bhn[3], bln[3];
        #pragma unroll
        for (int j = 0; j < 3; ++j)
            bhn[j] = *(const uint4*)(bbase + (size_t)kb * 12288 + j * 1024);
        if (topic) {
            #pragma unroll
            for (int j = 0; j < 3; ++j)
                bln[j] = *(const uint4*)(bbase + (size_t)kb * 12288 + j * 1024 + 512);
        }
        // A loads for kc+2
        const int ka = (kc + 2 < 64) ? kc + 2 : 63;
        float4 fa0 = *(const float4*)(fb0 + ka * 32);
        float4 fa1 = *(const float4*)(fb1 + ka * 32);

        // convert chunk kc+1 -> other buffer
        if (kc < 63) cw((kc + 1) & 1, a10, a11);

        // A fragments from buf kc&1 (stride 40 halfs: 16B-aligned, 2-way banks)
        const int cb = kc & 1;
        half8 fh[4], fl[4];
        #pragma unroll
        for (int i = 0; i < 4; ++i) {
            HU th;
            th.u = *(const uint4*)(aS + (size_t)((cb * 2 + 0) * 64 + i * 16 + lm) * 40 + lq * 8);
            fh[i] = th.v;
        }
        if (topic) {
            #pragma unroll
            for (int i = 0; i < 4; ++i) {
                HU tl;
                tl.u = *(const uint4*)(aS + (size_t)((cb * 2 + 1) * 64 + i * 16 + lm) * 40 + lq * 8);
                fl[i] = tl.v;
            }
        }

        if (topic) {
            #pragma unroll
            for (int j = 0; j < 3; ++j) {
                HU h8, l8; h8.u = bh[j]; l8.u = bl[j];
                #pragma unroll
                for (int i = 0; i < 4; ++i) {
                    acc[i][j] = __builtin_amdgcn_mfma_f32_16x16x32_f16(fh[i], h8.v, acc[i][j], 0, 0, 0);
                    acc[i][j] = __builtin_amdgcn_mfma_f32_16x16x32_f16(fh[i], l8.v, acc[i][j], 0, 0, 0);
                    acc[i][j] = __builtin_amdgcn_mfma_f32_16x16x32_f16(fl[i], h8.v, acc[i][j], 0, 0, 0);
                }
            }
        } else {
            #pragma unroll
            for (int j = 0; j < 3; ++j) {
                HU h8; h8.u = bh[j];
                #pragma unroll
                for (int i = 0; i < 4; ++i)
                    acc[i][j] = __builtin_amdgcn_mfma_f32_16x16x32_f16(fh[i], h8.v, acc[i][j], 0, 0, 0);
            }
        }

        sync_lds_only();

        a10 = fa0; a11 = fa1;
        #pragma unroll
        for (int j = 0; j < 3; ++j) bh[j] = bhn[j];
        if (topic) {
            #pragma unroll
            for (int j = 0; j < 3; ++j) bl[j] = bln[j];
        }
    }

    // ssq: 8 lanes (tid&7) share each row
    ssq0 += __shfl_xor(ssq0, 1, 64); ssq1 += __shfl_xor(ssq1, 1, 64);
    ssq0 += __shfl_xor(ssq0, 2, 64); ssq1 += __shfl_xor(ssq1, 2, 64);
    ssq0 += __shfl_xor(ssq0, 4, 64); ssq1 += __shfl_xor(ssq1, 4, 64);
    if ((tid & 7) == 0) { ssqf[srow] = ssq0; ssqf[32 + srow] = ssq1; }
    __syncthreads();   // all aS reads done before scores overwrite

    // dump scores (D layout: row = lq*4+r, col = lm)
    #pragma unroll
    for (int i = 0; i < 4; ++i)
        #pragma unroll
        for (int j = 0; j < 3; ++j)
            #pragma unroll
            for (int r = 0; r < 4; ++r)
                scores[(size_t)(i * 16 + lq * 4 + r) * SPAD + nq * 48 + j * 16 + lm] = acc[i][j][r];
    __syncthreads();

    // epilogue: one thread per row
    if (tid < 64) {
        const int r = tid;
        const float inv = TAU_F / fmaxf(sqrtf(ssqf[r]), 1e-12f);
        const float* sc = scores + (size_t)r * SPAD;
        float lg[9];
        float dmax = -1e30f;
        #pragma unroll
        for (int d = 0; d < 9; ++d) {
            const float* v = sc + d * 10;          // topic rows 0..89
            const float* u = sc + 96 + d * 10;     // domain rows 96..185
            float mx = v[0];
            #pragma unroll
            for (int m = 1; m < 10; ++m) mx = fmaxf(mx, v[m]);
            float ssum = 0.f, dot = 0.f;
            #pragma unroll
            for (int m = 0; m < 10; ++m) {
                const float p = __expf((v[m] - mx) * inv);
                ssum += p;
                dot = fmaf(p, u[m], dot);
            }
            const float lgt = (dot / ssum) * inv;
            lg[d] = lgt;
            dmax = fmaxf(dmax, lgt);
        }
        float s2 = 0.f;
        #pragma unroll
        for (int d = 0; d < 9; ++d) { const float p = __expf(lg[d] - dmax); lg[d] = p; s2 += p; }
        const float r2 = 1.0f / s2;
        #pragma unroll
        for (int d = 0; d < 9; ++d)
            out[(size_t)(row0 + r) * 9 + d] = lg[d] * r2;
    }
}

extern "C" void kernel_launch(void* const* d_in, const int* in_sizes, int n_in,
                              void* d_out, int out_size, void* d_ws, size_t ws_size,
                              hipStream_t stream) {
    const float* feature = (const float*)d_in[0];
    const float* Wt      = (const float*)d_in[1];
    const float* Wd      = (const float*)d_in[2];
    const float* mem     = (const float*)d_in[3];
    const int*   cat     = (const int*)d_in[4];

    // ws: P (6.3 MB) | gB 1.57 MB @50331648
    float* P  = (float*)d_ws;
    unsigned short* gB = (unsigned short*)((char*)d_ws + 50331648);
    float* out = (float*)d_out;

    gproj2<<<256, 256, 0, stream>>>(Wt, Wd, mem, cat, P);
    split_g3<<<192, 256, 0, stream>>>(P, gB);
    fused_mfma7<<<256, 256, 0, stream>>>(feature, gB, out);
}